// Round 6
// baseline (149.131 us; speedup 1.0000x reference)
//
#include <hip/hip_runtime.h>
#include <math.h>

#define NB 8
#define H 64
#define W 64
#define C 128
#define G 8
#define GC 16
#define P 9
#define NPIX (NB * H * W)     // 32768
#define N_OFF 144
#define N_MSK 72
#define PXB 32                // pixels per block (half row)
#define PK_IN_ELEMS   (8 * 4 * 64 * 8)    // 16384
#define PK_COMB_ELEMS (14 * 4 * 64 * 8)   // 28672
#define PK_OUT_ELEMS  (8 * 4 * 64 * 8)    // 16384

using bf16x8 = __attribute__((ext_vector_type(8))) short;
using f32x4  = __attribute__((ext_vector_type(4))) float;
using u32x4  = __attribute__((ext_vector_type(4))) unsigned;

__device__ __forceinline__ short f2bf(float f) {
    union { float fv; unsigned u; } v; v.fv = f;
    unsigned r = v.u + 0x7fffu + ((v.u >> 16) & 1u);
    return (short)(r >> 16);
}

// ---------------- K0: pack weights into MFMA B-fragment order, bf16 --------
// B frag for (nt,kt): lane l, elem i -> k = kt*32 + (l>>4)*8 + i ; n = nt*16 + (l&15)
__global__ __launch_bounds__(256) void k_pack(
    const float* __restrict__ w_in, const float* __restrict__ w_off,
    const float* __restrict__ w_msk, const float* __restrict__ w_out,
    short* __restrict__ pk_in, short* __restrict__ pk_comb, short* __restrict__ pk_out)
{
    const int tid = blockIdx.x * 256 + threadIdx.x;
    int p, which;
    if (tid < PK_IN_ELEMS) { p = tid; which = 0; }
    else if (tid < PK_IN_ELEMS + PK_COMB_ELEMS) { p = tid - PK_IN_ELEMS; which = 1; }
    else if (tid < PK_IN_ELEMS + PK_COMB_ELEMS + PK_OUT_ELEMS) { p = tid - PK_IN_ELEMS - PK_COMB_ELEMS; which = 2; }
    else return;
    const int e = p & 7, lane = (p >> 3) & 63, kt = (p >> 9) & 3, nt = p >> 11;
    const int k = kt * 32 + (lane >> 4) * 8 + e;
    const int n = nt * 16 + (lane & 15);
    float v;
    if (which == 0) {
        v = w_in[k * C + n];
        pk_in[p] = f2bf(v);
    } else if (which == 1) {
        if (n < N_OFF) v = w_off[k * N_OFF + n];
        else if (n < N_OFF + N_MSK) v = w_msk[k * N_MSK + (n - N_OFF)];
        else v = 0.f;
        pk_comb[p] = f2bf(v);
    } else {
        v = w_out[k * C + n];
        pk_out[p] = f2bf(v);
    }
}

// ---- K_front: dwconv+LN+GELU -> x1 (bf16, pre-swizzled, in out slots) -----
// ----           + input-proj MFMA -> xproj (group-planar bf16)        -----
// block = 32 px (half row); n = bid&7 (XCD pin), local = bid>>3
__global__ __launch_bounds__(256, 4) void k_front(
    const float* __restrict__ x, const float* __restrict__ dw_w,
    const float* __restrict__ dw_b, const float* __restrict__ ln_g,
    const float* __restrict__ ln_b, const short* __restrict__ pk_in,
    const float* __restrict__ b_in, unsigned short* __restrict__ xproj,
    float* __restrict__ outbuf)
{
    __shared__ __align__(16) short xa[PXB * C];   // 8 KB bf16 swizzled x (MFMA A)
    __shared__ float part[PXB][9][2];
    __shared__ float stats[PXB][2];

    const int t = threadIdx.x;
    const int n = blockIdx.x & 7;
    const int local = blockIdx.x >> 3;
    const int y = local >> 1;
    const int xb = (local & 1) * PXB;
    const int gpix0 = (n * H + y) * W + xb;

    const int px = t >> 3;          // 0..31
    const int c8 = t & 7;           // channel chunk (16 ch)
    const int c0 = c8 * 16;
    const int gpx = gpix0 + px;

    // ---- depthwise 3x3 (zeros pad), 16 ch per thread ----
    float a[16];
    #pragma unroll
    for (int q = 0; q < 4; ++q) {
        f32x4 v = *(const f32x4*)(dw_b + c0 + q * 4);
        #pragma unroll
        for (int e = 0; e < 4; ++e) a[q * 4 + e] = v[e];
    }
    #pragma unroll
    for (int ky = 0; ky < 3; ++ky) {
        const int yy = y + ky - 1;
        if (yy < 0 || yy >= H) continue;
        #pragma unroll
        for (int kx = 0; kx < 3; ++kx) {
            const int xx = xb + px + kx - 1;
            if (xx < 0 || xx >= W) continue;
            const float* xp = x + ((size_t)(n * H + yy) * W + xx) * C + c0;
            const float* wp = dw_w + (ky * 3 + kx) * C + c0;
            #pragma unroll
            for (int q = 0; q < 4; ++q) {
                f32x4 xv = *(const f32x4*)(xp + q * 4);
                f32x4 wv = *(const f32x4*)(wp + q * 4);
                #pragma unroll
                for (int e = 0; e < 4; ++e)
                    a[q * 4 + e] = fmaf(xv[e], wv[e], a[q * 4 + e]);
            }
        }
    }
    // stash center pixel x as bf16 into xa (swizzled) for input-proj MFMA
    {
        const float* cp = x + (size_t)gpx * C + c0;
        const int sw = (px & 7) << 4;
        #pragma unroll
        for (int h = 0; h < 2; ++h) {
            f32x4 v0 = *(const f32x4*)(cp + h * 8);
            f32x4 v1 = *(const f32x4*)(cp + h * 8 + 4);
            bf16x8 pk;
            #pragma unroll
            for (int e = 0; e < 4; ++e) { pk[e] = f2bf(v0[e]); pk[4 + e] = f2bf(v1[e]); }
            *(bf16x8*)((char*)xa + px * 256 + ((c8 * 32 + h * 16) ^ sw)) = pk;
        }
    }
    // LN partials
    {
        float s = 0.f, sq = 0.f;
        #pragma unroll
        for (int cc = 0; cc < 16; ++cc) { s += a[cc]; sq = fmaf(a[cc], a[cc], sq); }
        part[px][c8][0] = s;
        part[px][c8][1] = sq;
    }
    __syncthreads();
    if (t < PXB) {
        float S = 0.f, Q = 0.f;
        #pragma unroll
        for (int q = 0; q < 8; ++q) { S += part[t][q][0]; Q += part[t][q][1]; }
        const float mu = S * (1.f / C);
        const float va = Q * (1.f / C) - mu * mu;
        stats[t][0] = mu;
        stats[t][1] = rsqrtf(va + 1e-6f);
    }
    __syncthreads();

    // LN affine + GELU -> x1 bf16, PRE-SWIZZLED block layout, into out slots
    {
        const float mu = stats[px][0], rs = stats[px][1];
        char* dst = (char*)outbuf + (size_t)gpix0 * 512;   // 8 KB x1 region
        const int sw = (px & 7) << 4;
        #pragma unroll
        for (int h = 0; h < 2; ++h) {
            bf16x8 pk;
            #pragma unroll
            for (int e = 0; e < 8; ++e) {
                const int cc = h * 8 + e;
                float v = (a[cc] - mu) * rs * ln_g[c0 + cc] + ln_b[c0 + cc];
                pk[e] = f2bf(v * 0.5f * (1.f + erff(v * 0.70710678118654752f)));
            }
            *(bf16x8*)(dst + px * 256 + ((c8 * 32 + h * 16) ^ sw)) = pk;
        }
    }
    __syncthreads();

    // ---- input-proj MFMA -> xproj group-planar ----
    {
        const int w = t >> 6, l = t & 63;
        const int mtile = w >> 1, nseg = w & 1;
        const int m = mtile * 16 + (l & 15);
        const int sw = (m & 7) << 4;
        bf16x8 af[4];
        #pragma unroll
        for (int kt = 0; kt < 4; ++kt)
            af[kt] = *(const bf16x8*)((char*)xa + m * 256 + ((kt * 64 + (l >> 4) * 16) ^ sw));
        const int prow = gpix0 + mtile * 16 + (l >> 4) * 4;
        #pragma unroll
        for (int i = 0; i < 4; ++i) {
            const int nt = nseg * 4 + i;
            f32x4 acc = {0.f, 0.f, 0.f, 0.f};
            const short* bp = pk_in + nt * 2048 + l * 8;
            #pragma unroll
            for (int kt = 0; kt < 4; ++kt) {
                bf16x8 b = *(const bf16x8*)(bp + kt * 512);
                acc = __builtin_amdgcn_mfma_f32_16x16x32_bf16(af[kt], b, acc, 0, 0, 0);
            }
            const float bias = b_in[nt * 16 + (l & 15)];
            #pragma unroll
            for (int r = 0; r < 4; ++r)
                xproj[(size_t)(nt * NPIX + prow + r) * 16 + (l & 15)] =
                    (unsigned short)f2bf(acc[r] + bias);
        }
    }
}

// ---- K_back: offs/mask MFMA + softmax + sampling + out-proj ----
// block = 32 px; reads pre-swizzled x1 from out slots, writes final out.
__global__ __launch_bounds__(256, 4) void k_back(
    const unsigned short* __restrict__ xproj, const short* __restrict__ pk_comb,
    const float* __restrict__ b_off, const float* __restrict__ b_msk,
    const short* __restrict__ pk_out, const float* __restrict__ b_out,
    float* __restrict__ out)
{
    __shared__ __align__(16) short x1s[PXB * C];  // 8 KB; reused as smp
    __shared__ unsigned opair[N_MSK * 33];        // 9.5 KB bf16 offset pairs [gp][px]
    __shared__ float mlT[N_MSK * 33];             // 9.5 KB mask logits [gp][px]

    const int t = threadIdx.x;
    const int n = blockIdx.x & 7;
    const int local = blockIdx.x >> 3;
    const int y = local >> 1;
    const int xb = (local & 1) * PXB;
    const int gpix0 = (n * H + y) * W + xb;

    // ---- phase 1: linear copy of pre-swizzled x1 (8 KB) into LDS ----
    {
        const char* src = (const char*)out + (size_t)gpix0 * 512;
        #pragma unroll
        for (int it = 0; it < 2; ++it) {
            const int off = it * 4096 + t * 16;
            *(bf16x8*)((char*)x1s + off) = *(const bf16x8*)(src + off);
        }
    }
    __syncthreads();

    // ---- phase 2: offset(144)+mask(72) MFMA ----
    {
        const int w = t >> 6, l = t & 63;
        const int mtile = w >> 1, nseg = w & 1;
        const int m = mtile * 16 + (l & 15);
        const int sw = (m & 7) << 4;
        bf16x8 af[4];
        #pragma unroll
        for (int kt = 0; kt < 4; ++kt)
            af[kt] = *(const bf16x8*)((char*)x1s + m * 256 + ((kt * 64 + (l >> 4) * 16) ^ sw));
        const int pr0 = mtile * 16 + (l >> 4) * 4;
        #pragma unroll
        for (int i = 0; i < 7; ++i) {
            const int nt = nseg * 7 + i;
            f32x4 acc = {0.f, 0.f, 0.f, 0.f};
            const short* bp = pk_comb + nt * 2048 + l * 8;
            #pragma unroll
            for (int kt = 0; kt < 4; ++kt) {
                bf16x8 b = *(const bf16x8*)(bp + kt * 512);
                acc = __builtin_amdgcn_mfma_f32_16x16x32_bf16(af[kt], b, acc, 0, 0, 0);
            }
            const int col = nt * 16 + (l & 15);
            if (col < N_OFF) {
                const float bias = b_off[col];
                const int gp = col >> 1, half = col & 1;
                #pragma unroll
                for (int r = 0; r < 4; ++r)
                    ((unsigned short*)opair)[(gp * 33 + pr0 + r) * 2 + half] =
                        (unsigned short)f2bf(acc[r] + bias);
            } else if (col < N_OFF + N_MSK) {
                const float bias = b_msk[col - N_OFF];
                #pragma unroll
                for (int r = 0; r < 4; ++r)
                    mlT[(col - N_OFF) * 33 + pr0 + r] = acc[r] + bias;
            }
        }
    }
    __syncthreads();

    // ---- phase 3+4: softmax (regs) + sampling; thread = (px, g) ----
    {
        const int px = t >> 3, g = t & 7;
        const int sw = (px & 7) << 4;
        float lg[P];
        unsigned ov[P];
        #pragma unroll
        for (int p = 0; p < P; ++p) {
            lg[p] = mlT[(g * P + p) * 33 + px];
            ov[p] = opair[(g * P + p) * 33 + px];
        }
        float mx = lg[0];
        #pragma unroll
        for (int i = 1; i < P; ++i) mx = fmaxf(mx, lg[i]);
        float pr[P], s = 0.f;
        #pragma unroll
        for (int i = 0; i < P; ++i) { pr[i] = expf(lg[i] - mx); s += pr[i]; }
        const float inv = 1.0f / s;

        const unsigned short* plane = xproj + (size_t)(g * NPIX + n * H * W) * 16;
        float acc16[16];
        #pragma unroll
        for (int q = 0; q < 16; ++q) acc16[q] = 0.f;
        #pragma unroll
        for (int p = 0; p < P; ++p) {
            const unsigned v = ov[p];
            const float offx = __uint_as_float(v << 16);
            const float offy = __uint_as_float(v & 0xffff0000u);
            const float mk = pr[p] * inv;
            const float ux = (float)(xb + px + (p / 3) - 1) + offx;
            const float uy = (float)(y + (p % 3) - 1) + offy;
            const float fx = floorf(ux), fy = floorf(uy);
            const float wx = ux - fx, wy = uy - fy;
            const int x0 = (int)fx, y0 = (int)fy;
            float w00 = mk * (1.f - wx) * (1.f - wy);
            float w10 = mk * wx * (1.f - wy);
            float w01 = mk * (1.f - wx) * wy;
            float w11 = mk * wx * wy;
            if (!((x0 >= 0) & (x0 < W)))       { w00 = 0.f; w01 = 0.f; }
            if (!((x0 >= -1) & (x0 < W - 1)))  { w10 = 0.f; w11 = 0.f; }
            if (!((y0 >= 0) & (y0 < H)))       { w00 = 0.f; w10 = 0.f; }
            if (!((y0 >= -1) & (y0 < H - 1)))  { w01 = 0.f; w11 = 0.f; }
            const int x0c = min(max(x0, 0), W - 1), x1c = min(max(x0 + 1, 0), W - 1);
            const int y0c = min(max(y0, 0), H - 1), y1c = min(max(y0 + 1, 0), H - 1);
            const u32x4* p00 = (const u32x4*)(plane + (size_t)(y0c * W + x0c) * 16);
            const u32x4* p10 = (const u32x4*)(plane + (size_t)(y0c * W + x1c) * 16);
            const u32x4* p01 = (const u32x4*)(plane + (size_t)(y1c * W + x0c) * 16);
            const u32x4* p11 = (const u32x4*)(plane + (size_t)(y1c * W + x1c) * 16);
            #pragma unroll
            for (int q = 0; q < 2; ++q) {
                u32x4 v00 = p00[q], v10 = p10[q], v01 = p01[q], v11 = p11[q];
                #pragma unroll
                for (int e = 0; e < 4; ++e) {
                    const float l00 = __uint_as_float(v00[e] << 16);
                    const float h00 = __uint_as_float(v00[e] & 0xffff0000u);
                    const float l10 = __uint_as_float(v10[e] << 16);
                    const float h10 = __uint_as_float(v10[e] & 0xffff0000u);
                    const float l01 = __uint_as_float(v01[e] << 16);
                    const float h01 = __uint_as_float(v01[e] & 0xffff0000u);
                    const float l11 = __uint_as_float(v11[e] << 16);
                    const float h11 = __uint_as_float(v11[e] & 0xffff0000u);
                    acc16[q * 8 + 2 * e]     += fmaf(w00, l00, fmaf(w10, l10,
                                                 fmaf(w01, l01, w11 * l11)));
                    acc16[q * 8 + 2 * e + 1] += fmaf(w00, h00, fmaf(w10, h10,
                                                 fmaf(w01, h01, w11 * h11)));
                }
            }
        }
        __syncthreads();   // everyone done reading x1s/opair/mlT
        #pragma unroll
        for (int h = 0; h < 2; ++h) {
            bf16x8 pk;
            #pragma unroll
            for (int e = 0; e < 8; ++e) pk[e] = f2bf(acc16[h * 8 + e]);
            *(bf16x8*)((char*)x1s + px * 256 + ((g * 32 + h * 16) ^ sw)) = pk;
        }
    }
    __syncthreads();

    // ---- phase 5: output projection via MFMA ----
    {
        const int w = t >> 6, l = t & 63;
        const int mtile = w >> 1, nseg = w & 1;
        const int m = mtile * 16 + (l & 15);
        const int sw = (m & 7) << 4;
        bf16x8 af[4];
        #pragma unroll
        for (int kt = 0; kt < 4; ++kt)
            af[kt] = *(const bf16x8*)((char*)x1s + m * 256 + ((kt * 64 + (l >> 4) * 16) ^ sw));
        const int row0 = gpix0 + mtile * 16 + (l >> 4) * 4;
        #pragma unroll
        for (int i = 0; i < 4; ++i) {
            const int nt = nseg * 4 + i;
            f32x4 acc = {0.f, 0.f, 0.f, 0.f};
            const short* bp = pk_out + nt * 2048 + l * 8;
            #pragma unroll
            for (int kt = 0; kt < 4; ++kt) {
                bf16x8 b = *(const bf16x8*)(bp + kt * 512);
                acc = __builtin_amdgcn_mfma_f32_16x16x32_bf16(af[kt], b, acc, 0, 0, 0);
            }
            const int col = nt * 16 + (l & 15);
            const float bias = b_out[col];
            #pragma unroll
            for (int r = 0; r < 4; ++r)
                out[(size_t)(row0 + r) * C + col] = acc[r] + bias;
        }
    }
}

extern "C" void kernel_launch(void* const* d_in, const int* in_sizes, int n_in,
                              void* d_out, int out_size, void* d_ws, size_t ws_size,
                              hipStream_t stream)
{
    const float* x     = (const float*)d_in[0];
    const float* w_in  = (const float*)d_in[1];
    const float* b_in  = (const float*)d_in[2];
    const float* dw_w  = (const float*)d_in[3];
    const float* dw_b  = (const float*)d_in[4];
    const float* ln_g  = (const float*)d_in[5];
    const float* ln_b  = (const float*)d_in[6];
    const float* w_off = (const float*)d_in[7];
    const float* b_off = (const float*)d_in[8];
    const float* w_msk = (const float*)d_in[9];
    const float* b_msk = (const float*)d_in[10];
    const float* w_out = (const float*)d_in[11];
    const float* b_out = (const float*)d_in[12];

    short* pk_in   = (short*)d_ws;
    short* pk_comb = pk_in + PK_IN_ELEMS;
    short* pk_out  = pk_comb + PK_COMB_ELEMS;
    unsigned short* xproj = (unsigned short*)(pk_out + PK_OUT_ELEMS);  // 8.4 MB planar bf16
    float* out     = (float*)d_out;

    hipLaunchKernelGGL(k_pack, dim3(240), dim3(256), 0, stream,
                       w_in, w_off, w_msk, w_out, pk_in, pk_comb, pk_out);
    hipLaunchKernelGGL(k_front, dim3(NPIX / PXB), dim3(256), 0, stream,
                       x, dw_w, dw_b, ln_g, ln_b, pk_in, b_in, xproj, out);
    hipLaunchKernelGGL(k_back, dim3(NPIX / PXB), dim3(256), 0, stream,
                       xproj, pk_comb, b_off, b_msk, pk_out, b_out, out);
}

// Round 7
// 102.971 us; speedup vs baseline: 1.4483x; 1.4483x over previous
//
#include <hip/hip_runtime.h>
#include <math.h>

#define NB 8
#define H 64
#define W 64
#define C 128
#define G 8
#define GC 16
#define P 9
#define NPIX (NB * H * W)     // 32768
#define N_OFF 144
#define N_MSK 72
#define PK_IN_ELEMS   (8 * 4 * 64 * 8)    // 16384
#define PK_COMB_ELEMS (14 * 4 * 64 * 8)   // 28672
#define PK_OUT_ELEMS  (8 * 4 * 64 * 8)    // 16384

using bf16x8 = __attribute__((ext_vector_type(8))) short;
using f32x4  = __attribute__((ext_vector_type(4))) float;
using u32x4  = __attribute__((ext_vector_type(4))) unsigned;

__device__ __forceinline__ short f2bf(float f) {
    union { float fv; unsigned u; } v; v.fv = f;
    unsigned r = v.u + 0x7fffu + ((v.u >> 16) & 1u);
    return (short)(r >> 16);
}

// ---------------- K0: pack weights into MFMA B-fragment order, bf16 --------
__global__ __launch_bounds__(256) void k_pack(
    const float* __restrict__ w_in, const float* __restrict__ w_off,
    const float* __restrict__ w_msk, const float* __restrict__ w_out,
    short* __restrict__ pk_in, short* __restrict__ pk_comb, short* __restrict__ pk_out)
{
    const int tid = blockIdx.x * 256 + threadIdx.x;
    int p, which;
    if (tid < PK_IN_ELEMS) { p = tid; which = 0; }
    else if (tid < PK_IN_ELEMS + PK_COMB_ELEMS) { p = tid - PK_IN_ELEMS; which = 1; }
    else if (tid < PK_IN_ELEMS + PK_COMB_ELEMS + PK_OUT_ELEMS) { p = tid - PK_IN_ELEMS - PK_COMB_ELEMS; which = 2; }
    else return;
    const int e = p & 7, lane = (p >> 3) & 63, kt = (p >> 9) & 3, nt = p >> 11;
    const int k = kt * 32 + (lane >> 4) * 8 + e;
    const int n = nt * 16 + (lane & 15);
    float v;
    if (which == 0) {
        v = w_in[k * C + n];
        pk_in[p] = f2bf(v);
    } else if (which == 1) {
        if (n < N_OFF) v = w_off[k * N_OFF + n];
        else if (n < N_OFF + N_MSK) v = w_msk[k * N_MSK + (n - N_OFF)];
        else v = 0.f;
        pk_comb[p] = f2bf(v);
    } else {
        v = w_out[k * C + n];
        pk_out[p] = f2bf(v);
    }
}

// ---- K_front: dwconv+LN+GELU -> x1 (bf16 pre-swizzled into out slots) -----
// ----          + input-proj MFMA (nt-partitioned) -> planar bf16 xproj ----
// block = one image row (64 px); n = bid&7 (XCD pin), y = bid>>3
__global__ __launch_bounds__(256, 2) void k_front(
    const float* __restrict__ x, const float* __restrict__ dw_w,
    const float* __restrict__ dw_b, const float* __restrict__ ln_g,
    const float* __restrict__ ln_b, const short* __restrict__ pk_in,
    const float* __restrict__ b_in, unsigned short* __restrict__ xproj,
    float* __restrict__ outbuf)
{
    __shared__ __align__(16) short xa[64 * C];   // 16 KB bf16 swizzled x row (MFMA A)
    __shared__ float part[64][4][2];
    __shared__ float stats[64][2];

    const int t = threadIdx.x;
    const int n = blockIdx.x & 7;
    const int y = blockIdx.x >> 3;
    const int px = t >> 2;          // 0..63 = x coordinate
    const int cs = t & 3;           // channel chunk (32 ch)
    const int c0 = cs * 32;
    const int gpix0 = (n * H + y) * W;
    const int gpx = gpix0 + px;

    // ---- depthwise 3x3 (zeros pad) ----
    float a[32];
    #pragma unroll
    for (int q = 0; q < 8; ++q) {
        f32x4 v = *(const f32x4*)(dw_b + c0 + q * 4);
        #pragma unroll
        for (int e = 0; e < 4; ++e) a[q * 4 + e] = v[e];
    }
    #pragma unroll
    for (int ky = 0; ky < 3; ++ky) {
        const int yy = y + ky - 1;
        if (yy < 0 || yy >= H) continue;
        #pragma unroll
        for (int kx = 0; kx < 3; ++kx) {
            const int xx = px + kx - 1;
            if (xx < 0 || xx >= W) continue;
            const float* xp = x + ((size_t)(n * H + yy) * W + xx) * C + c0;
            const float* wp = dw_w + (ky * 3 + kx) * C + c0;
            #pragma unroll
            for (int q = 0; q < 8; ++q) {
                f32x4 xv = *(const f32x4*)(xp + q * 4);
                f32x4 wv = *(const f32x4*)(wp + q * 4);
                #pragma unroll
                for (int e = 0; e < 4; ++e)
                    a[q * 4 + e] = fmaf(xv[e], wv[e], a[q * 4 + e]);
            }
        }
    }
    // stash center pixel as bf16 into xa (swizzled) for input-proj MFMA
    {
        const float* cp = x + (size_t)gpx * C + c0;
        const int sw = (px & 7) << 4;
        #pragma unroll
        for (int j = 0; j < 4; ++j) {
            f32x4 v0 = *(const f32x4*)(cp + j * 8);
            f32x4 v1 = *(const f32x4*)(cp + j * 8 + 4);
            bf16x8 pk;
            #pragma unroll
            for (int e = 0; e < 4; ++e) { pk[e] = f2bf(v0[e]); pk[4 + e] = f2bf(v1[e]); }
            *(bf16x8*)((char*)xa + px * 256 + ((cs * 64 + j * 16) ^ sw)) = pk;
        }
    }
    // LN partials
    {
        float s = 0.f, sq = 0.f;
        #pragma unroll
        for (int cc = 0; cc < 32; ++cc) { s += a[cc]; sq = fmaf(a[cc], a[cc], sq); }
        part[px][cs][0] = s;
        part[px][cs][1] = sq;
    }
    __syncthreads();
    if (t < 64) {
        float S = 0.f, Q = 0.f;
        #pragma unroll
        for (int q = 0; q < 4; ++q) { S += part[t][q][0]; Q += part[t][q][1]; }
        const float mu = S * (1.f / C);
        const float va = Q * (1.f / C) - mu * mu;
        stats[t][0] = mu;
        stats[t][1] = rsqrtf(va + 1e-6f);
    }
    __syncthreads();

    // LN affine + GELU -> x1 bf16, pre-swizzled, into out slot bytes 0..255
    {
        const float mu = stats[px][0], rs = stats[px][1];
        char* dst = (char*)outbuf + (size_t)gpx * 512;
        const int sw = (px & 7) << 4;
        #pragma unroll
        for (int j = 0; j < 4; ++j) {
            bf16x8 pk;
            #pragma unroll
            for (int e = 0; e < 8; ++e) {
                const int cc = j * 8 + e;
                float v = (a[cc] - mu) * rs * ln_g[c0 + cc] + ln_b[c0 + cc];
                pk[e] = f2bf(v * 0.5f * (1.f + erff(v * 0.70710678118654752f)));
            }
            *(bf16x8*)(dst + ((cs * 64 + j * 16) ^ sw)) = pk;
        }
    }

    // ---- input-proj MFMA, nt-partitioned (each B-frag feeds 4 MFMAs) ----
    {
        const int w = t >> 6, l = t & 63;
        const int swA = (l & 7) << 4;
        #pragma unroll
        for (int i = 0; i < 2; ++i) {
            const int nt = w + i * 4;
            bf16x8 bf[4];
            const short* bp = pk_in + nt * 2048 + l * 8;
            #pragma unroll
            for (int kt = 0; kt < 4; ++kt) bf[kt] = *(const bf16x8*)(bp + kt * 512);
            const int col = nt * 16 + (l & 15);
            const float bias = b_in[col];
            #pragma unroll
            for (int mt = 0; mt < 4; ++mt) {
                const int m = mt * 16 + (l & 15);
                f32x4 acc = {0.f, 0.f, 0.f, 0.f};
                #pragma unroll
                for (int kt = 0; kt < 4; ++kt) {
                    bf16x8 af = *(const bf16x8*)((char*)xa + m * 256 +
                                                 ((kt * 64 + (l >> 4) * 16) ^ swA));
                    acc = __builtin_amdgcn_mfma_f32_16x16x32_bf16(af, bf[kt], acc, 0, 0, 0);
                }
                const int prow = gpix0 + mt * 16 + (l >> 4) * 4;
                #pragma unroll
                for (int r = 0; r < 4; ++r)
                    xproj[(size_t)(nt * NPIX + prow + r) * 16 + (l & 15)] =
                        (unsigned short)f2bf(acc[r] + bias);
            }
        }
    }
}

// ---- K_mid: offset/mask GEMM + softmax -> 448 B/px record in out slots ----
// record: bytes 0-287 = 144 bf16 offsets; 288-447 = 8 groups x 10 bf16 probs
__global__ __launch_bounds__(256, 2) void k_mid(
    const short* __restrict__ pk_comb, const float* __restrict__ b_off,
    const float* __restrict__ b_msk, float* __restrict__ out)
{
    __shared__ __align__(16) short x1s[64 * C];      // 16 KB
    __shared__ unsigned short recs[64 * 224];        // 28 KB staging (448 B/px)

    const int t = threadIdx.x;
    const int gpix0 = ((blockIdx.x & 7) * H + (blockIdx.x >> 3)) * W;

    // phase 1: linear copy of pre-swizzled x1 into LDS
    {
        const int px = t >> 2, q = t & 3;
        const char* src = (const char*)out + (size_t)(gpix0 + px) * 512;
        #pragma unroll
        for (int c = 0; c < 4; ++c) {
            const int byte = q * 64 + c * 16;
            *(bf16x8*)((char*)x1s + px * 256 + byte) = *(const bf16x8*)(src + byte);
        }
    }
    __syncthreads();

    // phase 2: MFMA, nt-partitioned
    {
        const int w = t >> 6, l = t & 63;
        const int swA = (l & 7) << 4;
        for (int i = 0; i < 4; ++i) {
            const int nt = w + i * 4;
            if (nt >= 14) break;
            bf16x8 bf[4];
            const short* bp = pk_comb + nt * 2048 + l * 8;
            #pragma unroll
            for (int kt = 0; kt < 4; ++kt) bf[kt] = *(const bf16x8*)(bp + kt * 512);
            const int col = nt * 16 + (l & 15);
            int dcol = col;
            float bias = 0.f;
            bool valid = true;
            if (col < N_OFF) bias = b_off[col];
            else {
                const int cm = col - N_OFF;
                if (cm < N_MSK) {
                    const int g = (cm * 57) >> 9;
                    dcol = 144 + g * 10 + (cm - 9 * g);
                    bias = b_msk[cm];
                } else valid = false;
            }
            #pragma unroll
            for (int mt = 0; mt < 4; ++mt) {
                const int m = mt * 16 + (l & 15);
                f32x4 acc = {0.f, 0.f, 0.f, 0.f};
                #pragma unroll
                for (int kt = 0; kt < 4; ++kt) {
                    bf16x8 af = *(const bf16x8*)((char*)x1s + m * 256 +
                                                 ((kt * 64 + (l >> 4) * 16) ^ swA));
                    acc = __builtin_amdgcn_mfma_f32_16x16x32_bf16(af, bf[kt], acc, 0, 0, 0);
                }
                if (valid) {
                    const int pr0 = mt * 16 + (l >> 4) * 4;
                    #pragma unroll
                    for (int r = 0; r < 4; ++r)
                        recs[(pr0 + r) * 224 + dcol] = (unsigned short)f2bf(acc[r] + bias);
                }
            }
        }
    }
    __syncthreads();

    // phase 3: softmax in place on the prob slots
    #pragma unroll
    for (int it = 0; it < 2; ++it) {
        const int idx = t + it * 256;
        const int px = idx & 63, g = idx >> 6;
        unsigned short* row = recs + px * 224 + 144 + g * 10;
        float lg[P];
        #pragma unroll
        for (int p = 0; p < P; ++p) lg[p] = __uint_as_float(((unsigned)row[p]) << 16);
        float mx = lg[0];
        #pragma unroll
        for (int p2 = 1; p2 < P; ++p2) mx = fmaxf(mx, lg[p2]);
        float e[P], s = 0.f;
        #pragma unroll
        for (int p2 = 0; p2 < P; ++p2) { e[p2] = expf(lg[p2] - mx); s += e[p2]; }
        const float inv = 1.0f / s;
        #pragma unroll
        for (int p2 = 0; p2 < P; ++p2) row[p2] = (unsigned short)f2bf(e[p2] * inv);
    }
    __syncthreads();

    // phase 4: coalesced copy of records to out slots (bytes 0..447)
    {
        const int px = t >> 2, q = t & 3;
        const char* srcL = (const char*)recs + px * 448;
        char* dst = (char*)out + (size_t)(gpix0 + px) * 512;
        #pragma unroll
        for (int c = 0; c < 7; ++c) {
            const int byte = q * 112 + c * 16;
            *(bf16x8*)(dst + byte) = *(const bf16x8*)(srcL + byte);
        }
    }
}

// ---- K_samp: deformable bilinear gather + output projection ----
__global__ __launch_bounds__(256, 2) void k_samp(
    const unsigned short* __restrict__ xproj, const short* __restrict__ pk_out,
    const float* __restrict__ b_out, float* __restrict__ out)
{
    __shared__ __align__(16) short smp[64 * C];   // 16 KB sampled features

    const int t = threadIdx.x;
    const int n = blockIdx.x & 7;
    const int y = blockIdx.x >> 3;
    const int gpix0 = (n * H + y) * W;

    // gather: lane = px (coalesced taps), 2 groups per thread
    {
        const int px = t & 63, gg = t >> 6;
        const int sw = (px & 7) << 4;
        const char* slot = (const char*)out + (size_t)(gpix0 + px) * 512;
        #pragma unroll
        for (int gi = 0; gi < 2; ++gi) {
            const int g = gg + gi * 4;
            // probs (post-softmax bf16)
            float pr[P];
            {
                const unsigned* pb = (const unsigned*)(slot + 288 + 20 * g);
                #pragma unroll
                for (int i = 0; i < 4; ++i) {
                    const unsigned u = pb[i];
                    pr[2 * i] = __uint_as_float(u << 16);
                    pr[2 * i + 1] = __uint_as_float(u & 0xffff0000u);
                }
                pr[8] = __uint_as_float(pb[4] << 16);
            }
            const unsigned* ob = (const unsigned*)(slot + 36 * g);
            const unsigned short* plane = xproj + (size_t)(g * NPIX + n * H * W) * 16;
            float acc16[16];
            #pragma unroll
            for (int q = 0; q < 16; ++q) acc16[q] = 0.f;
            #pragma unroll
            for (int p = 0; p < P; ++p) {
                const unsigned v = ob[p];
                const float offx = __uint_as_float(v << 16);
                const float offy = __uint_as_float(v & 0xffff0000u);
                const float mk = pr[p];
                const float ux = (float)(px + (p / 3) - 1) + offx;
                const float uy = (float)(y + (p % 3) - 1) + offy;
                const float fx = floorf(ux), fy = floorf(uy);
                const float wx = ux - fx, wy = uy - fy;
                const int x0 = (int)fx, y0 = (int)fy;
                float w00 = mk * (1.f - wx) * (1.f - wy);
                float w10 = mk * wx * (1.f - wy);
                float w01 = mk * (1.f - wx) * wy;
                float w11 = mk * wx * wy;
                if (!((x0 >= 0) & (x0 < W)))       { w00 = 0.f; w01 = 0.f; }
                if (!((x0 >= -1) & (x0 < W - 1)))  { w10 = 0.f; w11 = 0.f; }
                if (!((y0 >= 0) & (y0 < H)))       { w00 = 0.f; w10 = 0.f; }
                if (!((y0 >= -1) & (y0 < H - 1)))  { w01 = 0.f; w11 = 0.f; }
                const int x0c = min(max(x0, 0), W - 1), x1c = min(max(x0 + 1, 0), W - 1);
                const int y0c = min(max(y0, 0), H - 1), y1c = min(max(y0 + 1, 0), H - 1);
                const u32x4* p00 = (const u32x4*)(plane + (size_t)(y0c * W + x0c) * 16);
                const u32x4* p10 = (const u32x4*)(plane + (size_t)(y0c * W + x1c) * 16);
                const u32x4* p01 = (const u32x4*)(plane + (size_t)(y1c * W + x0c) * 16);
                const u32x4* p11 = (const u32x4*)(plane + (size_t)(y1c * W + x1c) * 16);
                #pragma unroll
                for (int q = 0; q < 2; ++q) {
                    u32x4 v00 = p00[q], v10 = p10[q], v01 = p01[q], v11 = p11[q];
                    #pragma unroll
                    for (int e = 0; e < 4; ++e) {
                        const float l00 = __uint_as_float(v00[e] << 16);
                        const float h00 = __uint_as_float(v00[e] & 0xffff0000u);
                        const float l10 = __uint_as_float(v10[e] << 16);
                        const float h10 = __uint_as_float(v10[e] & 0xffff0000u);
                        const float l01 = __uint_as_float(v01[e] << 16);
                        const float h01 = __uint_as_float(v01[e] & 0xffff0000u);
                        const float l11 = __uint_as_float(v11[e] << 16);
                        const float h11 = __uint_as_float(v11[e] & 0xffff0000u);
                        acc16[q * 8 + 2 * e]     += fmaf(w00, l00, fmaf(w10, l10,
                                                     fmaf(w01, l01, w11 * l11)));
                        acc16[q * 8 + 2 * e + 1] += fmaf(w00, h00, fmaf(w10, h10,
                                                     fmaf(w01, h01, w11 * h11)));
                    }
                }
            }
            #pragma unroll
            for (int h = 0; h < 2; ++h) {
                bf16x8 pk;
                #pragma unroll
                for (int e = 0; e < 8; ++e) pk[e] = f2bf(acc16[h * 8 + e]);
                *(bf16x8*)((char*)smp + px * 256 + ((g * 32 + h * 16) ^ sw)) = pk;
            }
        }
    }
    __syncthreads();

    // output projection, nt-partitioned (overwrites slots with final fp32)
    {
        const int w = t >> 6, l = t & 63;
        const int swA = (l & 7) << 4;
        #pragma unroll
        for (int i = 0; i < 2; ++i) {
            const int nt = w + i * 4;
            bf16x8 bf[4];
            const short* bp = pk_out + nt * 2048 + l * 8;
            #pragma unroll
            for (int kt = 0; kt < 4; ++kt) bf[kt] = *(const bf16x8*)(bp + kt * 512);
            const int col = nt * 16 + (l & 15);
            const float bias = b_out[col];
            #pragma unroll
            for (int mt = 0; mt < 4; ++mt) {
                const int m = mt * 16 + (l & 15);
                f32x4 acc = {0.f, 0.f, 0.f, 0.f};
                #pragma unroll
                for (int kt = 0; kt < 4; ++kt) {
                    bf16x8 af = *(const bf16x8*)((char*)smp + m * 256 +
                                                 ((kt * 64 + (l >> 4) * 16) ^ swA));
                    acc = __builtin_amdgcn_mfma_f32_16x16x32_bf16(af, bf[kt], acc, 0, 0, 0);
                }
                const int row0 = gpix0 + mt * 16 + (l >> 4) * 4;
                #pragma unroll
                for (int r = 0; r < 4; ++r)
                    out[(size_t)(row0 + r) * C + col] = acc[r] + bias;
            }
        }
    }
}

extern "C" void kernel_launch(void* const* d_in, const int* in_sizes, int n_in,
                              void* d_out, int out_size, void* d_ws, size_t ws_size,
                              hipStream_t stream)
{
    const float* x     = (const float*)d_in[0];
    const float* w_in  = (const float*)d_in[1];
    const float* b_in  = (const float*)d_in[2];
    const float* dw_w  = (const float*)d_in[3];
    const float* dw_b  = (const float*)d_in[4];
    const float* ln_g  = (const float*)d_in[5];
    const float* ln_b  = (const float*)d_in[6];
    const float* w_off = (const float*)d_in[7];
    const float* b_off = (const float*)d_in[8];
    const float* w_msk = (const float*)d_in[9];
    const float* b_msk = (const float*)d_in[10];
    const float* w_out = (const float*)d_in[11];
    const float* b_out = (const float*)d_in[12];

    short* pk_in   = (short*)d_ws;
    short* pk_comb = pk_in + PK_IN_ELEMS;
    short* pk_out  = pk_comb + PK_COMB_ELEMS;
    unsigned short* xproj = (unsigned short*)(pk_out + PK_OUT_ELEMS);  // 8.4 MB planar bf16
    float* out     = (float*)d_out;

    hipLaunchKernelGGL(k_pack, dim3(240), dim3(256), 0, stream,
                       w_in, w_off, w_msk, w_out, pk_in, pk_comb, pk_out);
    hipLaunchKernelGGL(k_front, dim3(NB * H), dim3(256), 0, stream,
                       x, dw_w, dw_b, ln_g, ln_b, pk_in, b_in, xproj, out);
    hipLaunchKernelGGL(k_mid, dim3(NB * H), dim3(256), 0, stream,
                       pk_comb, b_off, b_msk, out);
    hipLaunchKernelGGL(k_samp, dim3(NB * H), dim3(256), 0, stream,
                       xproj, pk_out, b_out, out);
}

// Round 8
// 84.310 us; speedup vs baseline: 1.7688x; 1.2213x over previous
//
#include <hip/hip_runtime.h>
#include <math.h>

#define NB 8
#define H 64
#define W 64
#define C 128
#define G 8
#define GC 16
#define P 9
#define NPIX (NB * H * W)     // 32768
#define N_OFF 144
#define N_MSK 72
#define PXB 32
#define RECW 232              // record row stride in u16 (464 B, padded from 448)
#define PK_IN_ELEMS   (8 * 4 * 64 * 8)    // 16384
#define PK_COMB_ELEMS (14 * 4 * 64 * 8)   // 28672
#define PK_OUT_ELEMS  (8 * 4 * 64 * 8)    // 16384

using bf16x8 = __attribute__((ext_vector_type(8))) short;
using f32x4  = __attribute__((ext_vector_type(4))) float;
using u32x4  = __attribute__((ext_vector_type(4))) unsigned;

__device__ __forceinline__ short f2bf(float f) {
    union { float fv; unsigned u; } v; v.fv = f;
    unsigned r = v.u + 0x7fffu + ((v.u >> 16) & 1u);
    return (short)(r >> 16);
}

// ---------------- K0: pack weights into MFMA B-fragment order, bf16 --------
__global__ __launch_bounds__(256) void k_pack(
    const float* __restrict__ w_in, const float* __restrict__ w_off,
    const float* __restrict__ w_msk, const float* __restrict__ w_out,
    short* __restrict__ pk_in, short* __restrict__ pk_comb, short* __restrict__ pk_out)
{
    const int tid = blockIdx.x * 256 + threadIdx.x;
    int p, which;
    if (tid < PK_IN_ELEMS) { p = tid; which = 0; }
    else if (tid < PK_IN_ELEMS + PK_COMB_ELEMS) { p = tid - PK_IN_ELEMS; which = 1; }
    else if (tid < PK_IN_ELEMS + PK_COMB_ELEMS + PK_OUT_ELEMS) { p = tid - PK_IN_ELEMS - PK_COMB_ELEMS; which = 2; }
    else return;
    const int e = p & 7, lane = (p >> 3) & 63, kt = (p >> 9) & 3, nt = p >> 11;
    const int k = kt * 32 + (lane >> 4) * 8 + e;
    const int n = nt * 16 + (lane & 15);
    float v;
    if (which == 0) {
        v = w_in[k * C + n];
        pk_in[p] = f2bf(v);
    } else if (which == 1) {
        if (n < N_OFF) v = w_off[k * N_OFF + n];
        else if (n < N_OFF + N_MSK) v = w_msk[k * N_MSK + (n - N_OFF)];
        else v = 0.f;
        pk_comb[p] = f2bf(v);
    } else {
        v = w_out[k * C + n];
        pk_out[p] = f2bf(v);
    }
}

// ---- K_fm: dwconv+LN+GELU (LDS) + inproj MFMA -> xproj planar ----
// ----       + offset/mask MFMA + softmax -> 448B/px records in out slots ---
// block = 32 px; n = bid&7 (XCD pin), local = bid>>3
__global__ __launch_bounds__(256, 2) void k_fm(
    const float* __restrict__ x, const float* __restrict__ dw_w,
    const float* __restrict__ dw_b, const float* __restrict__ ln_g,
    const float* __restrict__ ln_b, const short* __restrict__ pk_in,
    const float* __restrict__ b_in, const short* __restrict__ pk_comb,
    const float* __restrict__ b_off, const float* __restrict__ b_msk,
    unsigned short* __restrict__ xproj, float* __restrict__ out)
{
    __shared__ __align__(16) short xa[PXB * C];       // 8 KB center-x bf16 swizzled
    __shared__ __align__(16) short x1s[PXB * C];      // 8 KB GELU(LN(dwconv)) bf16
    __shared__ unsigned short recs[PXB * RECW];       // 14.5 KB records
    __shared__ float part[PXB][8][2];
    __shared__ float stats[PXB][2];

    const int t = threadIdx.x;
    const int n = blockIdx.x & 7;
    const int local = blockIdx.x >> 3;
    const int y = local >> 1;
    const int xb = (local & 1) * PXB;
    const int gpix0 = (n * H + y) * W + xb;

    const int px = t >> 3;          // 0..31
    const int c8 = t & 7;
    const int c0 = c8 * 16;
    const int gpx = gpix0 + px;

    // ---- phase A: depthwise 3x3 (zeros pad), 16 ch/thread ----
    float a[16];
    #pragma unroll
    for (int q = 0; q < 4; ++q) {
        f32x4 v = *(const f32x4*)(dw_b + c0 + q * 4);
        #pragma unroll
        for (int e = 0; e < 4; ++e) a[q * 4 + e] = v[e];
    }
    #pragma unroll
    for (int ky = 0; ky < 3; ++ky) {
        const int yy = y + ky - 1;
        if (yy < 0 || yy >= H) continue;
        #pragma unroll
        for (int kx = 0; kx < 3; ++kx) {
            const int xx = xb + px + kx - 1;
            if (xx < 0 || xx >= W) continue;
            const float* xp = x + ((size_t)(n * H + yy) * W + xx) * C + c0;
            const float* wp = dw_w + (ky * 3 + kx) * C + c0;
            #pragma unroll
            for (int q = 0; q < 4; ++q) {
                f32x4 xv = *(const f32x4*)(xp + q * 4);
                f32x4 wv = *(const f32x4*)(wp + q * 4);
                #pragma unroll
                for (int e = 0; e < 4; ++e)
                    a[q * 4 + e] = fmaf(xv[e], wv[e], a[q * 4 + e]);
            }
        }
    }
    // stash center pixel bf16 -> xa (swizzled) for inproj
    {
        const float* cp = x + (size_t)gpx * C + c0;
        const int sw = (px & 7) << 4;
        #pragma unroll
        for (int h = 0; h < 2; ++h) {
            f32x4 v0 = *(const f32x4*)(cp + h * 8);
            f32x4 v1 = *(const f32x4*)(cp + h * 8 + 4);
            bf16x8 pk;
            #pragma unroll
            for (int e = 0; e < 4; ++e) { pk[e] = f2bf(v0[e]); pk[4 + e] = f2bf(v1[e]); }
            *(bf16x8*)((char*)xa + px * 256 + ((c8 * 32 + h * 16) ^ sw)) = pk;
        }
    }
    // LN partials
    {
        float s = 0.f, sq = 0.f;
        #pragma unroll
        for (int cc = 0; cc < 16; ++cc) { s += a[cc]; sq = fmaf(a[cc], a[cc], sq); }
        part[px][c8][0] = s;
        part[px][c8][1] = sq;
    }
    __syncthreads();
    if (t < PXB) {
        float S = 0.f, Q = 0.f;
        #pragma unroll
        for (int q = 0; q < 8; ++q) { S += part[t][q][0]; Q += part[t][q][1]; }
        const float mu = S * (1.f / C);
        const float va = Q * (1.f / C) - mu * mu;
        stats[t][0] = mu;
        stats[t][1] = rsqrtf(va + 1e-6f);
    }
    __syncthreads();
    // LN affine + GELU -> x1s (LDS only)
    {
        const float mu = stats[px][0], rs = stats[px][1];
        const int sw = (px & 7) << 4;
        #pragma unroll
        for (int h = 0; h < 2; ++h) {
            bf16x8 pk;
            #pragma unroll
            for (int e = 0; e < 8; ++e) {
                const int cc = h * 8 + e;
                float v = (a[cc] - mu) * rs * ln_g[c0 + cc] + ln_b[c0 + cc];
                pk[e] = f2bf(v * 0.5f * (1.f + erff(v * 0.70710678118654752f)));
            }
            *(bf16x8*)((char*)x1s + px * 256 + ((c8 * 32 + h * 16) ^ sw)) = pk;
        }
    }
    __syncthreads();

    // ---- phase B: inproj MFMA (xa) + comb MFMA (x1s), nt-partitioned ----
    {
        const int w = t >> 6, l = t & 63;
        const int swA = (l & 7) << 4;
        // hoisted A-fragments
        bf16x8 aA[2][4], aB[2][4];
        #pragma unroll
        for (int mt = 0; mt < 2; ++mt) {
            const int m = mt * 16 + (l & 15);
            #pragma unroll
            for (int kt = 0; kt < 4; ++kt) {
                const int byte = m * 256 + ((kt * 64 + (l >> 4) * 16) ^ swA);
                aA[mt][kt] = *(const bf16x8*)((char*)xa + byte);
                aB[mt][kt] = *(const bf16x8*)((char*)x1s + byte);
            }
        }
        // input projection -> planar xproj
        #pragma unroll
        for (int i = 0; i < 2; ++i) {
            const int nt = w + i * 4;
            bf16x8 bf[4];
            const short* bp = pk_in + nt * 2048 + l * 8;
            #pragma unroll
            for (int kt = 0; kt < 4; ++kt) bf[kt] = *(const bf16x8*)(bp + kt * 512);
            const float bias = b_in[nt * 16 + (l & 15)];
            #pragma unroll
            for (int mt = 0; mt < 2; ++mt) {
                f32x4 acc = {0.f, 0.f, 0.f, 0.f};
                #pragma unroll
                for (int kt = 0; kt < 4; ++kt)
                    acc = __builtin_amdgcn_mfma_f32_16x16x32_bf16(aA[mt][kt], bf[kt], acc, 0, 0, 0);
                const int prow = gpix0 + mt * 16 + (l >> 4) * 4;
                #pragma unroll
                for (int r = 0; r < 4; ++r)
                    xproj[(size_t)(nt * NPIX + prow + r) * 16 + (l & 15)] =
                        (unsigned short)f2bf(acc[r] + bias);
            }
        }
        // offset/mask projection -> recs
        #pragma unroll
        for (int i = 0; i < 4; ++i) {
            const int nt = w + i * 4;
            if (nt < 14) {
                bf16x8 bf[4];
                const short* bp = pk_comb + nt * 2048 + l * 8;
                #pragma unroll
                for (int kt = 0; kt < 4; ++kt) bf[kt] = *(const bf16x8*)(bp + kt * 512);
                const int col = nt * 16 + (l & 15);
                int dcol = col;
                float bias = 0.f;
                bool valid = true;
                if (col < N_OFF) bias = b_off[col];
                else {
                    const int cm = col - N_OFF;
                    if (cm < N_MSK) {
                        const int g = (cm * 57) >> 9;
                        dcol = 144 + g * 10 + (cm - 9 * g);
                        bias = b_msk[cm];
                    } else valid = false;
                }
                #pragma unroll
                for (int mt = 0; mt < 2; ++mt) {
                    f32x4 acc = {0.f, 0.f, 0.f, 0.f};
                    #pragma unroll
                    for (int kt = 0; kt < 4; ++kt)
                        acc = __builtin_amdgcn_mfma_f32_16x16x32_bf16(aB[mt][kt], bf[kt], acc, 0, 0, 0);
                    if (valid) {
                        const int pr0 = mt * 16 + (l >> 4) * 4;
                        #pragma unroll
                        for (int r = 0; r < 4; ++r)
                            recs[(pr0 + r) * RECW + dcol] = (unsigned short)f2bf(acc[r] + bias);
                    }
                }
            }
        }
    }
    __syncthreads();

    // ---- phase C: softmax on prob slots (one (px,g) per thread) ----
    {
        const int spx = t >> 3, g = t & 7;
        unsigned short* row = recs + spx * RECW + 144 + g * 10;
        float lg[P];
        #pragma unroll
        for (int p = 0; p < P; ++p) lg[p] = __uint_as_float(((unsigned)row[p]) << 16);
        float mx = lg[0];
        #pragma unroll
        for (int p2 = 1; p2 < P; ++p2) mx = fmaxf(mx, lg[p2]);
        float e[P], s = 0.f;
        #pragma unroll
        for (int p2 = 0; p2 < P; ++p2) { e[p2] = expf(lg[p2] - mx); s += e[p2]; }
        const float inv = 1.0f / s;
        #pragma unroll
        for (int p2 = 0; p2 < P; ++p2) row[p2] = (unsigned short)f2bf(e[p2] * inv);
    }
    __syncthreads();

    // ---- phase D: coalesced record write to out slots ----
    {
        const int spx = t >> 3, q0 = t & 7;
        const char* srcL = (const char*)recs + spx * (RECW * 2);
        char* dst = (char*)out + (size_t)(gpix0 + spx) * 512;
        #pragma unroll
        for (int h = 0; h < 4; ++h) {
            const int q = q0 + h * 8;
            if (q < 28)
                *(bf16x8*)(dst + q * 16) = *(const bf16x8*)(srcL + q * 16);
        }
    }
}

// ---- K_samp: record staging + deformable gather + output projection ----
__global__ __launch_bounds__(256, 2) void k_samp(
    const unsigned short* __restrict__ xproj, const short* __restrict__ pk_out,
    const float* __restrict__ b_out, float* __restrict__ out)
{
    __shared__ __align__(16) short smp[PXB * C];       // 8 KB sampled bf16
    __shared__ unsigned short recsS[PXB * RECW];       // 14.5 KB records

    const int t = threadIdx.x;
    const int n = blockIdx.x & 7;
    const int local = blockIdx.x >> 3;
    const int y = local >> 1;
    const int xb = (local & 1) * PXB;
    const int gpix0 = (n * H + y) * W + xb;

    // ---- stage records (coalesced) ----
    {
        const int spx = t >> 3, q0 = t & 7;
        const char* src = (const char*)out + (size_t)(gpix0 + spx) * 512;
        char* dstL = (char*)recsS + spx * (RECW * 2);
        #pragma unroll
        for (int h = 0; h < 4; ++h) {
            const int q = q0 + h * 8;
            if (q < 28)
                *(bf16x8*)(dstL + q * 16) = *(const bf16x8*)(src + q * 16);
        }
    }
    __syncthreads();

    // ---- gather: thread = (px = t&31, g = t>>5) ----
    {
        const int px = t & 31, g = t >> 5;
        const int sw = (px & 7) << 4;
        const unsigned* rec32 = (const unsigned*)recsS + px * (RECW / 2);
        float pr[P];
        {
            const unsigned* pb = rec32 + 72 + 5 * g;   // u16 idx 144 + 10g
            #pragma unroll
            for (int i = 0; i < 4; ++i) {
                const unsigned u = pb[i];
                pr[2 * i] = __uint_as_float(u << 16);
                pr[2 * i + 1] = __uint_as_float(u & 0xffff0000u);
            }
            pr[8] = __uint_as_float(pb[4] << 16);
        }
        const unsigned* ob = rec32 + 9 * g;
        const unsigned short* plane = xproj + (size_t)(g * NPIX + n * H * W) * 16;
        float acc16[16];
        #pragma unroll
        for (int q = 0; q < 16; ++q) acc16[q] = 0.f;
        #pragma unroll
        for (int p = 0; p < P; ++p) {
            const unsigned v = ob[p];
            const float offx = __uint_as_float(v << 16);
            const float offy = __uint_as_float(v & 0xffff0000u);
            const float mk = pr[p];
            const float ux = (float)(xb + px + (p / 3) - 1) + offx;
            const float uy = (float)(y + (p % 3) - 1) + offy;
            const float fx = floorf(ux), fy = floorf(uy);
            const float wx = ux - fx, wy = uy - fy;
            const int x0 = (int)fx, y0 = (int)fy;
            float w00 = mk * (1.f - wx) * (1.f - wy);
            float w10 = mk * wx * (1.f - wy);
            float w01 = mk * (1.f - wx) * wy;
            float w11 = mk * wx * wy;
            if (!((x0 >= 0) & (x0 < W)))       { w00 = 0.f; w01 = 0.f; }
            if (!((x0 >= -1) & (x0 < W - 1)))  { w10 = 0.f; w11 = 0.f; }
            if (!((y0 >= 0) & (y0 < H)))       { w00 = 0.f; w10 = 0.f; }
            if (!((y0 >= -1) & (y0 < H - 1)))  { w01 = 0.f; w11 = 0.f; }
            const int x0c = min(max(x0, 0), W - 1), x1c = min(max(x0 + 1, 0), W - 1);
            const int y0c = min(max(y0, 0), H - 1), y1c = min(max(y0 + 1, 0), H - 1);
            const u32x4* p00 = (const u32x4*)(plane + (size_t)(y0c * W + x0c) * 16);
            const u32x4* p10 = (const u32x4*)(plane + (size_t)(y0c * W + x1c) * 16);
            const u32x4* p01 = (const u32x4*)(plane + (size_t)(y1c * W + x0c) * 16);
            const u32x4* p11 = (const u32x4*)(plane + (size_t)(y1c * W + x1c) * 16);
            #pragma unroll
            for (int q = 0; q < 2; ++q) {
                u32x4 v00 = p00[q], v10 = p10[q], v01 = p01[q], v11 = p11[q];
                #pragma unroll
                for (int e = 0; e < 4; ++e) {
                    const float l00 = __uint_as_float(v00[e] << 16);
                    const float h00 = __uint_as_float(v00[e] & 0xffff0000u);
                    const float l10 = __uint_as_float(v10[e] << 16);
                    const float h10 = __uint_as_float(v10[e] & 0xffff0000u);
                    const float l01 = __uint_as_float(v01[e] << 16);
                    const float h01 = __uint_as_float(v01[e] & 0xffff0000u);
                    const float l11 = __uint_as_float(v11[e] << 16);
                    const float h11 = __uint_as_float(v11[e] & 0xffff0000u);
                    acc16[q * 8 + 2 * e]     += fmaf(w00, l00, fmaf(w10, l10,
                                                 fmaf(w01, l01, w11 * l11)));
                    acc16[q * 8 + 2 * e + 1] += fmaf(w00, h00, fmaf(w10, h10,
                                                 fmaf(w01, h01, w11 * h11)));
                }
            }
        }
        #pragma unroll
        for (int h = 0; h < 2; ++h) {
            bf16x8 pk;
            #pragma unroll
            for (int e = 0; e < 8; ++e) pk[e] = f2bf(acc16[h * 8 + e]);
            *(bf16x8*)((char*)smp + px * 256 + ((g * 32 + h * 16) ^ sw)) = pk;
        }
    }
    __syncthreads();

    // ---- output projection, nt-partitioned ----
    {
        const int w = t >> 6, l = t & 63;
        const int swA = (l & 7) << 4;
        bf16x8 aS[2][4];
        #pragma unroll
        for (int mt = 0; mt < 2; ++mt) {
            const int m = mt * 16 + (l & 15);
            #pragma unroll
            for (int kt = 0; kt < 4; ++kt)
                aS[mt][kt] = *(const bf16x8*)((char*)smp + m * 256 +
                                              ((kt * 64 + (l >> 4) * 16) ^ swA));
        }
        #pragma unroll
        for (int i = 0; i < 2; ++i) {
            const int nt = w + i * 4;
            bf16x8 bf[4];
            const short* bp = pk_out + nt * 2048 + l * 8;
            #pragma unroll
            for (int kt = 0; kt < 4; ++kt) bf[kt] = *(const bf16x8*)(bp + kt * 512);
            const float bias = b_out[nt * 16 + (l & 15)];
            #pragma unroll
            for (int mt = 0; mt < 2; ++mt) {
                f32x4 acc = {0.f, 0.f, 0.f, 0.f};
                #pragma unroll
                for (int kt = 0; kt < 4; ++kt)
                    acc = __builtin_amdgcn_mfma_f32_16x16x32_bf16(aS[mt][kt], bf[kt], acc, 0, 0, 0);
                const int row0 = gpix0 + mt * 16 + (l >> 4) * 4;
                #pragma unroll
                for (int r = 0; r < 4; ++r)
                    out[(size_t)(row0 + r) * C + nt * 16 + (l & 15)] = acc[r] + bias;
            }
        }
    }
}

extern "C" void kernel_launch(void* const* d_in, const int* in_sizes, int n_in,
                              void* d_out, int out_size, void* d_ws, size_t ws_size,
                              hipStream_t stream)
{
    const float* x     = (const float*)d_in[0];
    const float* w_in  = (const float*)d_in[1];
    const float* b_in  = (const float*)d_in[2];
    const float* dw_w  = (const float*)d_in[3];
    const float* dw_b  = (const float*)d_in[4];
    const float* ln_g  = (const float*)d_in[5];
    const float* ln_b  = (const float*)d_in[6];
    const float* w_off = (const float*)d_in[7];
    const float* b_off = (const float*)d_in[8];
    const float* w_msk = (const float*)d_in[9];
    const float* b_msk = (const float*)d_in[10];
    const float* w_out = (const float*)d_in[11];
    const float* b_out = (const float*)d_in[12];

    short* pk_in   = (short*)d_ws;
    short* pk_comb = pk_in + PK_IN_ELEMS;
    short* pk_out  = pk_comb + PK_COMB_ELEMS;
    unsigned short* xproj = (unsigned short*)(pk_out + PK_OUT_ELEMS);  // 8.4 MB planar bf16
    float* out     = (float*)d_out;

    hipLaunchKernelGGL(k_pack, dim3(240), dim3(256), 0, stream,
                       w_in, w_off, w_msk, w_out, pk_in, pk_comb, pk_out);
    hipLaunchKernelGGL(k_fm, dim3(NPIX / PXB), dim3(256), 0, stream,
                       x, dw_w, dw_b, ln_g, ln_b, pk_in, b_in,
                       pk_comb, b_off, b_msk, xproj, out);
    hipLaunchKernelGGL(k_samp, dim3(NPIX / PXB), dim3(256), 0, stream,
                       xproj, pk_out, b_out, out);
}